// Round 5
// baseline (326.639 us; speedup 1.0000x reference)
//
#include <hip/hip_runtime.h>

#define LT_N 8192
#define CHUNK 2048   // floats per wave-chunk (8 KB)

// Native 4xf32 vector for __builtin_nontemporal_load (HIP_vector_type is not
// accepted by the builtin).
typedef float f32x4 __attribute__((ext_vector_type(4)));

// PROBE ROUND (fixed compile): R3 kernel + a second full read pass over the
// row (nontemporal loads, separate accumulator, result = 0.5*(p1+p2)).
// Purpose: calibrate the kernel's true share of dur_us, which is invisible in
// top-5 (swamped by >=161us harness fills). If dur_us rises by ~one HBM pass
// (~20-30us) or not at all, the single-pass kernel was at its ~20us traffic
// floor. If it rises ~80-160us, there's a hidden shared bottleneck.
__global__ __launch_bounds__(256, 4) void tril_matvec_kernel(
    const float* __restrict__ x,
    const float* __restrict__ W,
    float* __restrict__ y)
{
    __shared__ float partial[4];

    const int wave = threadIdx.x >> 6;
    const int lane = threadIdx.x & 63;
    const int r = LT_N - 1 - (int)blockIdx.x;   // longest rows first
    const int len = r + 1;
    const float* Wr = W + (size_t)r * LT_N;

    const int beg = wave * CHUNK;
    const int end = min(beg + CHUNK, len);

    float acc = 0.0f, acc2 = 0.0f;
    if (beg < len) {
        const int n = end - beg;               // 1..2048
        if (n == CHUNK) {
            const float* Wb = Wr + beg + lane * 4;
            const float* xb = x  + beg + lane * 4;
            // Pass 1: normal loads, 8 independent dwordx4 in flight.
            {
                f32x4 wv[8], xv[8];
                #pragma unroll
                for (int i = 0; i < 8; ++i) wv[i] = *(const f32x4*)(Wb + i * 256);
                #pragma unroll
                for (int i = 0; i < 8; ++i) xv[i] = *(const f32x4*)(xb + i * 256);
                #pragma unroll
                for (int i = 0; i < 8; ++i)
                    acc += wv[i].x * xv[i].x + wv[i].y * xv[i].y
                         + wv[i].z * xv[i].z + wv[i].w * xv[i].w;
            }
            // Pass 2: nontemporal loads (distinct instruction -> no CSE).
            {
                f32x4 wv[8], xv[8];
                #pragma unroll
                for (int i = 0; i < 8; ++i)
                    wv[i] = __builtin_nontemporal_load((const f32x4*)(Wb + i * 256));
                #pragma unroll
                for (int i = 0; i < 8; ++i) xv[i] = *(const f32x4*)(xb + i * 256);
                #pragma unroll
                for (int i = 0; i < 8; ++i)
                    acc2 += wv[i].x * xv[i].x + wv[i].y * xv[i].y
                          + wv[i].z * xv[i].z + wv[i].w * xv[i].w;
            }
        } else {
            const int n4 = n & ~3;
            for (int j = lane * 4; j < n4; j += 256) {
                f32x4 wv = *(const f32x4*)(Wr + beg + j);
                f32x4 xv = *(const f32x4*)(x  + beg + j);
                acc += wv.x * xv.x + wv.y * xv.y + wv.z * xv.z + wv.w * xv.w;
            }
            for (int j = lane * 4; j < n4; j += 256) {
                f32x4 wv = __builtin_nontemporal_load((const f32x4*)(Wr + beg + j));
                f32x4 xv = *(const f32x4*)(x + beg + j);
                acc2 += wv.x * xv.x + wv.y * xv.y + wv.z * xv.z + wv.w * xv.w;
            }
            const int rem = n - n4;
            if (lane < rem) {
                float v = Wr[beg + n4 + lane] * x[beg + n4 + lane];
                acc += v;
                acc2 += v;
            }
        }
    }

    acc = 0.5f * (acc + acc2);

    // Wave64 tree reduction.
    #pragma unroll
    for (int off = 32; off > 0; off >>= 1)
        acc += __shfl_down(acc, off, 64);

    if (lane == 0) partial[wave] = acc;
    __syncthreads();
    if (threadIdx.x == 0)
        y[r] = (partial[0] + partial[1]) + (partial[2] + partial[3]);
}

extern "C" void kernel_launch(void* const* d_in, const int* in_sizes, int n_in,
                              void* d_out, int out_size, void* d_ws, size_t ws_size,
                              hipStream_t stream)
{
    const float* x = (const float*)d_in[0];
    const float* W = (const float*)d_in[1];
    float* y = (float*)d_out;

    dim3 grid(LT_N);    // one block per row
    dim3 block(256);    // 4 waves
    tril_matvec_kernel<<<grid, block, 0, stream>>>(x, W, y);
}

// Round 6
// 324.088 us; speedup vs baseline: 1.0079x; 1.0079x over previous
//
#include <hip/hip_runtime.h>

#define LT_N 8192
#define CHUNK 2048   // floats per wave-chunk (8 KB)

// Lower-triangular matvec y[i] = sum_{j<=i} W[i,j]*x[j], N=8192.
// FINAL (probe reverted): one block (4 waves) per row, longest rows first;
// wave w scans columns [w*2048,(w+1)*2048) clipped to row length with 8
// independent global_load_dwordx4 in flight. x read from global (L2/L3-hot;
// no intra-block reuse, so LDS staging only adds latency).
//
// Ceiling evidence (R1-R5): three structurally different kernels land at
// 323.x us +-0.2%; doubling the triangle read (R5 probe) costs +3us. The
// kernel's share of dur_us is ~5-20us (triangle = 134 MB, L3-resident);
// the rest is fixed harness traffic (1GiB ws poison 161us + W restore).
__global__ __launch_bounds__(256, 4) void tril_matvec_kernel(
    const float* __restrict__ x,
    const float* __restrict__ W,
    float* __restrict__ y)
{
    __shared__ float partial[4];

    const int wave = threadIdx.x >> 6;
    const int lane = threadIdx.x & 63;
    const int r = LT_N - 1 - (int)blockIdx.x;   // longest rows first
    const int len = r + 1;
    const float* Wr = W + (size_t)r * LT_N;

    const int beg = wave * CHUNK;
    const int end = min(beg + CHUNK, len);

    float acc = 0.0f;
    if (beg < len) {
        const int n = end - beg;               // 1..2048
        if (n == CHUNK) {
            // Full chunk: 8 W-loads + 8 x-loads, all independent, then FMAs.
            const float* Wb = Wr + beg + lane * 4;
            const float* xb = x  + beg + lane * 4;
            float4 wv[8], xv[8];
            #pragma unroll
            for (int i = 0; i < 8; ++i) wv[i] = *(const float4*)(Wb + i * 256);
            #pragma unroll
            for (int i = 0; i < 8; ++i) xv[i] = *(const float4*)(xb + i * 256);
            #pragma unroll
            for (int i = 0; i < 8; ++i)
                acc += wv[i].x * xv[i].x + wv[i].y * xv[i].y
                     + wv[i].z * xv[i].z + wv[i].w * xv[i].w;
        } else {
            // Boundary chunk (last active wave of the row).
            const int n4 = n & ~3;
            for (int j = lane * 4; j < n4; j += 256) {
                float4 wv = *(const float4*)(Wr + beg + j);
                float4 xv = *(const float4*)(x  + beg + j);
                acc += wv.x * xv.x + wv.y * xv.y + wv.z * xv.z + wv.w * xv.w;
            }
            const int rem = n - n4;
            if (lane < rem)
                acc += Wr[beg + n4 + lane] * x[beg + n4 + lane];
        }
    }

    // Wave64 tree reduction.
    #pragma unroll
    for (int off = 32; off > 0; off >>= 1)
        acc += __shfl_down(acc, off, 64);

    if (lane == 0) partial[wave] = acc;      // inactive waves write 0
    __syncthreads();
    if (threadIdx.x == 0)
        y[r] = (partial[0] + partial[1]) + (partial[2] + partial[3]);
}

extern "C" void kernel_launch(void* const* d_in, const int* in_sizes, int n_in,
                              void* d_out, int out_size, void* d_ws, size_t ws_size,
                              hipStream_t stream)
{
    const float* x = (const float*)d_in[0];
    const float* W = (const float*)d_in[1];
    float* y = (float*)d_out;

    dim3 grid(LT_N);    // one block per row
    dim3 block(256);    // 4 waves
    tril_matvec_kernel<<<grid, block, 0, stream>>>(x, W, y);
}